// Round 7
// baseline (1385.103 us; speedup 1.0000x reference)
//
#include <hip/hip_runtime.h>
#include <cstdint>

typedef unsigned short u16;
typedef __bf16  bf16x8 __attribute__((ext_vector_type(8)));
typedef float   f32x4  __attribute__((ext_vector_type(4)));
typedef unsigned short u16x4 __attribute__((ext_vector_type(4)));
typedef unsigned short u16x8 __attribute__((ext_vector_type(8)));

#define S_LEN 3072
#define DMODEL 1024

__device__ __forceinline__ float bf2f(u16 u){ return __uint_as_float(((unsigned)u) << 16); }
__device__ __forceinline__ u16 f2bf(float f){
    unsigned u = __float_as_uint(f);
    return (u16)((u + 0x7fffu + ((u >> 16) & 1u)) >> 16);
}
// mode-aware element fetch -> bf16 bits (mode 0: bf16 input; mode 1: fp32 input)
__device__ __forceinline__ u16 cvld(const void* p, long i, int mode){
    return mode ? f2bf(((const float*)p)[i]) : ((const u16*)p)[i];
}

__device__ __forceinline__ void async16(const void* g, void* l){
    __builtin_amdgcn_global_load_lds(
        (const __attribute__((address_space(1))) unsigned int*)g,
        (__attribute__((address_space(3))) unsigned int*)l, 16, 0, 0);
}

// ---------------------------------------------------------------------------
// dtype sniffer (proven): flag[0]=1 if inputs are fp32, 0 if bf16; flag[1]=0.
// ---------------------------------------------------------------------------
__global__ void sniff_kernel(const u16* __restrict__ x, int* __restrict__ flag)
{
    __shared__ int r[256];
    int tid = threadIdx.x, w = 0;
    for (int j = tid; j < 4096; j += 256){
        int e = (x[j] >> 7) & 0xFF;
        if (e < 90 || e > 140) w++;
    }
    r[tid] = w; __syncthreads();
    for (int s = 128; s > 0; s >>= 1){ if (tid < s) r[tid] += r[tid + s]; __syncthreads(); }
    if (tid == 0){ flag[0] = (r[0] > 256) ? 1 : 0; flag[1] = 0; }
}

// ---------------------------------------------------------------------------
// LDS swizzle note (all MFMA kernels): logical (row m, 16B-chunk c) lives at
// physical chunk c ^ (m&7).  global_load_lds dest stays LINEAR (HW rule); the
// XOR is applied to the per-thread GLOBAL source chunk.  Reads use
// j = c ^ (lr&7) (fragment row ≡ lr mod 8) -> 2-way (free) bank access.
// ---------------------------------------------------------------------------

// ---------------------------------------------------------------------------
// FUSED ATTENTION (max-free softmax: exp args bounded, no running max, so
// partial sums add with NO rescaling).  Per block: 32 Q-rows of one head.
// Loop over 48 KV-tiles of 64: S=QK^T (Q in regs, K from LDS) -> exp ->
// P (32x64 bf16, swizzled LDS) -> barrier -> PV (V^T tile from LDS) -> barrier.
// Row-sums accumulate in regs; single divide in the epilogue.  Scores matrix
// is NEVER materialized (kills the 75 MB write + 151 MB read per layer).
// LDS: K dbuf 64K + V dbuf 64K + P 4K + rs 0.5K = 132.5 KB -> 1 block/CU.
// ---------------------------------------------------------------------------
__global__ __launch_bounds__(256)
void fused_attn(const u16* __restrict__ qkvh, u16* __restrict__ ctx)
{
    __shared__ __align__(16) u16 smem[67840];     // 132.5 KB
    u16*  Pb  = smem + 65536;                     // 32x64 bf16
    float* rsb = (float*)(smem + 67584);          // [4 waves][32 rows]

    const int tid  = threadIdx.x;
    const int lane = tid & 63, wid = tid >> 6;
    const int quad = lane >> 4, lr = lane & 15;
    const int jx = lr & 7;
    const int h = blockIdx.y;
    const int qbase = blockIdx.x * 32;

    const u16* Q  = qkvh + (long)qbase * DMODEL + h * 256;
    const u16* K  = qkvh + (long)S_LEN * DMODEL + h * 256;                    // [s][e]
    const u16* Vt = qkvh + (long)2 * S_LEN * DMODEL + (long)h * 256 * S_LEN;  // [e][s]

    // Q fragments in registers: row mt*16+lr, e-chunk (ks*4+quad)
    bf16x8 qf[2][8];
#pragma unroll
    for (int mt = 0; mt < 2; ++mt)
#pragma unroll
        for (int ks = 0; ks < 8; ++ks)
            qf[mt][ks] = *(const bf16x8*)(Q + (long)(mt*16 + lr) * DMODEL + (ks*4 + quad) * 8);

    f32x4 zero = {0.f, 0.f, 0.f, 0.f};
    f32x4 oa[2][4];
#pragma unroll
    for (int mt = 0; mt < 2; ++mt)
#pragma unroll
        for (int nt = 0; nt < 4; ++nt) oa[mt][nt] = zero;
    float rsp[2][4] = {{0.f,0.f,0.f,0.f},{0.f,0.f,0.f,0.f}};

    // staging maps: K-tile 64(kv)x256(e) = 2048 chunks; V-tile 256(e)x64(kv)
    const u16* kP[8]; const u16* vP[8]; int dOf[8];
#pragma unroll
    for (int i = 0; i < 8; ++i){
        int u = i * 256 + tid;
        int kr = u >> 5, kc = u & 31;
        kP[i] = K + (long)kr * DMODEL + (kc ^ (kr & 7)) * 8;
        int vr = u >> 3, vc = u & 7;
        vP[i] = Vt + (long)vr * S_LEN + (vc ^ (vr & 7)) * 8;
        dOf[i] = u * 8;
    }

    auto stageKV = [&](int it, int b){
        const int kv0 = it << 6;
        u16* Kd = smem + b * 16384;
        u16* Vd = smem + 32768 + b * 16384;
#pragma unroll
        for (int i = 0; i < 8; ++i) async16(kP[i] + (long)kv0 * DMODEL, Kd + dOf[i]);
#pragma unroll
        for (int i = 0; i < 8; ++i) async16(vP[i] + kv0, Vd + dOf[i]);
    };

    const float scale = 0.0625f;                  // 1/sqrt(256)
    stageKV(0, 0);
    __syncthreads();
    for (int it = 0; it < 48; ++it){
        const int cur = it & 1;
        if (it + 1 < 48) stageKV(it + 1, cur ^ 1);
        // ---- QK^T: S[32 q][16 kv] per wave (kv cols wid*16..) ----
        const u16* Kc = smem + cur * 16384;
        f32x4 sa0 = zero, sa1 = zero;
#pragma unroll
        for (int ks = 0; ks < 8; ++ks){
            const int j = (ks*4 + quad) ^ jx;
            bf16x8 kb = *(const bf16x8*)(Kc + (wid*16 + lr) * 256 + j*8);
            sa0 = __builtin_amdgcn_mfma_f32_16x16x32_bf16(qf[0][ks], kb, sa0, 0, 0, 0);
            sa1 = __builtin_amdgcn_mfma_f32_16x16x32_bf16(qf[1][ks], kb, sa1, 0, 0, 0);
        }
        // ---- exp + rowsum partials + swizzled P write ----
#pragma unroll
        for (int mt = 0; mt < 2; ++mt){
#pragma unroll
            for (int r = 0; r < 4; ++r){
                float e = __expf((mt ? sa1[r] : sa0[r]) * scale);   // |arg|<~2
                rsp[mt][r] += e;
                int m = mt*16 + quad*4 + r;
                Pb[m*64 + (((wid*2 + (lr >> 3)) ^ (m & 7)) * 8) + (lr & 7)] = f2bf(e);
            }
        }
        __syncthreads();        // P visible to all waves; prefetch drained
        // ---- PV: O[32][64 e] per wave (e cols wid*64..) ----
        const u16* Vc = smem + 32768 + cur * 16384;
#pragma unroll
        for (int ks = 0; ks < 2; ++ks){
            const int j = (ks*4 + quad) ^ jx;
            bf16x8 pa0 = *(const bf16x8*)(Pb + lr*64        + j*8);
            bf16x8 pa1 = *(const bf16x8*)(Pb + (16 + lr)*64 + j*8);
#pragma unroll
            for (int nt = 0; nt < 4; ++nt){
                bf16x8 vb = *(const bf16x8*)(Vc + (wid*64 + nt*16 + lr) * 64 + j*8);
                oa[0][nt] = __builtin_amdgcn_mfma_f32_16x16x32_bf16(pa0, vb, oa[0][nt], 0, 0, 0);
                oa[1][nt] = __builtin_amdgcn_mfma_f32_16x16x32_bf16(pa1, vb, oa[1][nt], 0, 0, 0);
            }
        }
        __syncthreads();        // all waves done with P/K/V[cur]
    }

    // ---- rowsums: 16-lane butterfly, cross-wave via LDS ----
#pragma unroll
    for (int mt = 0; mt < 2; ++mt)
#pragma unroll
        for (int r = 0; r < 4; ++r){
            float v = rsp[mt][r];
            v += __shfl_xor(v, 1, 64);
            v += __shfl_xor(v, 2, 64);
            v += __shfl_xor(v, 4, 64);
            v += __shfl_xor(v, 8, 64);
            if (lr == 0) rsb[wid*32 + mt*16 + quad*4 + r] = v;
        }
    __syncthreads();
    float inv[2][4];
#pragma unroll
    for (int mt = 0; mt < 2; ++mt)
#pragma unroll
        for (int r = 0; r < 4; ++r){
            int m = mt*16 + quad*4 + r;
            inv[mt][r] = 1.f / (rsb[m] + rsb[32 + m] + rsb[64 + m] + rsb[96 + m]);
        }

    // ---- epilogue: O * inv -> wave-private u16 repack -> coalesced store ----
    u16* scw = smem + (size_t)wid * (16 * 72);
    const int row_l = lane >> 2, cq = lane & 3;
#pragma unroll
    for (int mt = 0; mt < 2; ++mt){
#pragma unroll
        for (int nt = 0; nt < 4; ++nt)
#pragma unroll
            for (int r = 0; r < 4; ++r)
                scw[(quad*4 + r) * 72 + nt*16 + lr] = f2bf(oa[mt][nt][r] * inv[mt][r]);
        u16x8 p0 = *(const u16x8*)(scw + row_l * 72 + cq * 16);
        u16x8 p1 = *(const u16x8*)(scw + row_l * 72 + cq * 16 + 8);
        u16* cp = ctx + (long)(qbase + mt*16 + row_l) * DMODEL + h * 256 + wid * 64 + cq * 16;
        *(u16x8*)cp       = p0;
        *(u16x8*)(cp + 8) = p1;
    }
}

// ---------------------------------------------------------------------------
// NT GEMM 128x128 tile, DOUBLE-BUFFERED 2-phase prefetch + swizzled LDS.
// SPLIT>1: bf16 partials at sp*pStride + bat*cBS (pStride in elements).
// SPLIT==1 modes: 0 bf16(+bias), 1 QKV scatter (Q,K natural; V transposed),
//                 2 bias+ReLU.
// Wave layout: 2x2 waves, each owns a 64x64 quadrant (acc[4][4]).
// ---------------------------------------------------------------------------
template<int SPLIT, int MODE>
__global__ __launch_bounds__(256)
void gemm128(const u16* __restrict__ A, int lda,
             const u16* __restrict__ B, int ldb,
             void* __restrict__ Cv, int ldc,
             const u16* __restrict__ bias,
             int K, long aBS, long bBS, long cBS, long pStride,
             const float* __restrict__ rs)
{
    __shared__ __align__(16) u16 smem[4 * 128 * 64];     // 64 KB: 2x(A+B)
    u16* As0 = smem;
    u16* Bs0 = smem + 2 * 128 * 64;
    const int tid  = threadIdx.x;
    const int lane = tid & 63, wid = tid >> 6;
    const int wm = wid >> 1, wn = wid & 1;
    const int quad = lane >> 4, lr = lane & 15;
    const int jx = lr & 7;

    const int z   = blockIdx.z;
    const int bat = z / SPLIT;
    const int sp  = z % SPLIT;
    const int kLen = K / SPLIT;

    A += (long)bat * aBS + (long)blockIdx.x * 128 * lda + (long)sp * kLen;
    B += (long)bat * bBS + (long)blockIdx.y * 128 * ldb + (long)sp * kLen;

    f32x4 zero = {0.f, 0.f, 0.f, 0.f};
    f32x4 acc[4][4];
#pragma unroll
    for (int i = 0; i < 4; i++)
#pragma unroll
        for (int j = 0; j < 4; j++) acc[i][j] = zero;

    const u16* aP[4]; const u16* bP[4]; int ldst[4];
#pragma unroll
    for (int i = 0; i < 4; i++){
        int u = i * 256 + tid;
        int m = u >> 3, c = u & 7;
        int cs = c ^ (m & 7);                 // pre-swizzled global chunk
        aP[i] = A + (long)m * lda + cs * 8;
        bP[i] = B + (long)m * ldb + cs * 8;
        ldst[i] = u * 8;
    }

    auto stage = [&](int kt, int b){
        const int k0 = kt << 6;
        u16* Ad = As0 + b * (128 * 64);
        u16* Bd = Bs0 + b * (128 * 64);
#pragma unroll
        for (int i = 0; i < 4; i++) async16(aP[i] + k0, Ad + ldst[i]);
#pragma unroll
        for (int i = 0; i < 4; i++) async16(bP[i] + k0, Bd + ldst[i]);
    };

    const int kTiles = kLen >> 6;
    stage(0, 0);
    __syncthreads();                       // drains prologue loads (vmcnt 0)
    for (int kt = 0; kt < kTiles; ++kt){
        const int cur = kt & 1;
        if (kt + 1 < kTiles) stage(kt + 1, cur ^ 1);   // prefetch next tile
        const u16* Ac = As0 + cur * (128 * 64);
        const u16* Bc = Bs0 + cur * (128 * 64);
#pragma unroll
        for (int ks = 0; ks < 2; ++ks){
            const int j = (ks * 4 + quad) ^ jx;
            bf16x8 af[4], bfg[4];
#pragma unroll
            for (int t = 0; t < 4; t++){
                int m  = wm * 64 + t * 16 + lr;
                af[t]  = *(const bf16x8*)(Ac + (m * 8 + j) * 8);
                int n  = wn * 64 + t * 16 + lr;
                bfg[t] = *(const bf16x8*)(Bc + (n * 8 + j) * 8);
            }
#pragma unroll
            for (int mt = 0; mt < 4; mt++)
#pragma unroll
                for (int nt = 0; nt < 4; nt++)
                    acc[mt][nt] = __builtin_amdgcn_mfma_f32_16x16x32_bf16(
                        af[mt], bfg[nt], acc[mt][nt], 0, 0, 0);
        }
        __syncthreads();   // all waves done with buf[cur]; prefetch drained
    }

    const int rowBase = blockIdx.x * 128 + wm * 64;
    const int colBase = blockIdx.y * 128 + wn * 64;
    const int slabw = colBase >> 10;             // wave-uniform (128 | 1024)

    if (MODE == 1 && slabw == 2){
        // ---- V^T path: bias, per-16-col transpose in LDS (u16, stride 72),
        //      store along s.  Wave-private scratch: 16x72 u16 = 2304 B. ----
        u16* scw = smem + (size_t)wid * (16 * 72);
        const int e_l = lane >> 2, sh = lane & 3;
#pragma unroll
        for (int nt = 0; nt < 4; nt++){
            float bv2 = bf2f(bias[colBase + nt * 16 + lr]);
#pragma unroll
            for (int mt = 0; mt < 4; mt++){
                u16x4 pk;
#pragma unroll
                for (int r = 0; r < 4; r++) pk[r] = f2bf(acc[mt][nt][r] + bv2);
                *(u16x4*)(scw + lr * 72 + mt * 16 + quad * 4) = pk;
            }
            const int e_g = (colBase & 1023) + nt * 16 + e_l;
            u16* dst = (u16*)Cv + (long)2 * S_LEN * DMODEL + (long)e_g * S_LEN
                     + rowBase + sh * 16;
            *(u16x8*)(dst)     = *(const u16x8*)(scw + e_l * 72 + sh * 16);
            *(u16x8*)(dst + 8) = *(const u16x8*)(scw + e_l * 72 + sh * 16 + 8);
        }
        return;
    }

    // ---- generic path: per-mt wave-private fp32 repack, coalesced stores ----
    float* scw = (float*)smem + (size_t)wid * (16 * 68);   // 4352 B / wave
    const int row_l = lane >> 2, cq = lane & 3;
#pragma unroll
    for (int mt = 0; mt < 4; ++mt){
#pragma unroll
        for (int nt = 0; nt < 4; nt++)
#pragma unroll
            for (int r = 0; r < 4; r++)
                scw[(quad * 4 + r) * 68 + nt * 16 + lr] = acc[mt][nt][r];
        float vals[16];
#pragma unroll
        for (int j = 0; j < 4; j++)
            *(f32x4*)(vals + j * 4) = *(const f32x4*)(scw + row_l * 68 + cq * 16 + j * 4);
        const int row_g = rowBase + mt * 16 + row_l;
        const int colg  = colBase + cq * 16;
        float bv[16];
        if (SPLIT == 1 && bias){
            u16x8 b0 = *(const u16x8*)(bias + colg);
            u16x8 b1 = *(const u16x8*)(bias + colg + 8);
#pragma unroll
            for (int i = 0; i < 8; i++){ bv[i] = bf2f(b0[i]); bv[8 + i] = bf2f(b1[i]); }
        } else {
#pragma unroll
            for (int i = 0; i < 16; i++) bv[i] = 0.f;
        }
        u16x8 pk0, pk1;
#pragma unroll
        for (int i = 0; i < 16; i++){
            float v = vals[i] + bv[i];
            if (MODE == 2) v = fmaxf(v, 0.f);
            if (i < 8) pk0[i] = f2bf(v); else pk1[i - 8] = f2bf(v);
        }
        long idx;
        if (SPLIT > 1)      idx = (long)sp * pStride + (long)bat * cBS + (long)row_g * ldc + colg;
        else if (MODE == 1) idx = ((long)slabw * S_LEN + row_g) * DMODEL + (colg & 1023);
        else                idx = (long)bat * cBS + (long)row_g * ldc + colg;
        u16* cp = (u16*)Cv + idx;
        *(u16x8*)cp       = pk0;
        *(u16x8*)(cp + 8) = pk1;
    }
}

// ---------------------------------------------------------------------------
// merged per-layer prep: weight transposes + Wq|Wk|Wv copy + rowSums zero.
// grid.x = 7728, block (32,8).
// ---------------------------------------------------------------------------
__global__ __launch_bounds__(256)
void wprep(const int* __restrict__ flag, int l,
           const void* Wo, const void* Wf1, const void* Wf2, const void* Wh,
           const void* Wq, const void* Wk, const void* Wv,
           u16* __restrict__ WoT, u16* __restrict__ Wf1T,
           u16* __restrict__ Wf2T, u16* __restrict__ WhT,
           u16* __restrict__ Wcat, float* __restrict__ rowSums)
{
    const int mode = *flag;
    const int z = blockIdx.x;
    const int tx = threadIdx.x, ty = threadIdx.y;

    if (z >= 7680){
        int idx = (z - 7680) * 256 + ty * 32 + tx;   // < 12288
        rowSums[idx] = 0.f;
        return;
    }
    if (z >= 6144){
        int t = ty * 32 + tx;
        long base = (long)(z - 6144) * 2048;
#pragma unroll
        for (int j = 0; j < 8; j++){
            long g = base + j * 256 + t;
            int slab = (int)(g >> 20);
            long r = g & 1048575;
            const void* src = (slab == 0) ? Wq : (slab == 1) ? Wk : Wv;
            Wcat[g] = cvld(src, (long)l * 1048576 + r, mode);
        }
        return;
    }

    const void* in; u16* out; long ib; int R, C, rb, cb;
    if (z < 1024){
        in = Wo; out = WoT; ib = (long)l * 1048576; R = 1024; C = 1024;
        cb = z & 31; rb = z >> 5;
    } else if (z < 3072){
        int t = z - 1024;
        in = Wf1; out = Wf1T; ib = (long)l * 2097152; R = 1024; C = 2048;
        cb = t & 63; rb = t >> 6;
    } else if (z < 5120){
        int t = z - 3072;
        in = Wf2; out = Wf2T; ib = (long)l * 2097152; R = 2048; C = 1024;
        cb = t & 31; rb = t >> 5;
    } else {
        int t = z - 5120;
        int a = t >> 8, u = t & 255;
        in = Wh; out = WhT + (long)a * 262144;
        ib = (long)l * 1048576 + (long)a * 262144; R = 1024; C = 256;
        cb = u & 7; rb = u >> 3;
    }

    __shared__ u16 tbuf[32][34];
    int r0 = rb * 32, c0 = cb * 32;
#pragma unroll
    for (int j = 0; j < 4; j++){
        int r = r0 + ty + j * 8;
        tbuf[ty + j * 8][tx] = cvld(in, ib + (long)r * C + c0 + tx, mode);
    }
    __syncthreads();
#pragma unroll
    for (int j = 0; j < 4; j++){
        int c = c0 + ty + j * 8;
        out[(long)c * R + r0 + tx] = tbuf[tx][ty + j * 8];
    }
}

__global__ __launch_bounds__(256)
void init_h(const int* __restrict__ flag, const void* __restrict__ hin,
            float* __restrict__ h, u16* __restrict__ hbf)
{
    const int mode = *flag;
    long i = (long)blockIdx.x * 256 + threadIdx.x;
    u16 u = cvld(hin, i, mode);
    h[i]   = bf2f(u);
    hbf[i] = u;
}

// bias arena layout (elements)
#define OFF_BQKV 0
#define OFF_BH   12288
#define OFF_BO   16384
#define OFF_BF1  20480
#define OFF_BF2  28672
#define OFF_G1   32768
#define OFF_B1N  36864
#define OFF_G2   40960
#define OFF_B2N  45056
#define OFF_WHD  49152
#define OFF_BHD  53248
#define BIAS_TOT 53252

__global__ __launch_bounds__(256)
void cvt_biases(const int* __restrict__ flag,
                const void* bq, const void* bk, const void* bv, const void* bh,
                const void* bo, const void* bf1, const void* bf2,
                const void* g1, const void* b1n, const void* g2, const void* b2n,
                const void* whd, const void* bhd, u16* __restrict__ A)
{
    int i = blockIdx.x * 256 + threadIdx.x;
    if (i >= BIAS_TOT) return;
    const int mode = *flag;
    u16 v;
    if (i < OFF_BH){
        int l = i / 3072, r = i % 3072;
        const void* p = (r < 1024) ? bq : (r < 2048) ? bk : bv;
        v = cvld(p, (long)l * 1024 + (r & 1023), mode);
    }
    else if (i < OFF_BO)  v = cvld(bh,  i - OFF_BH, mode);
    else if (i < OFF_BF1) v = cvld(bo,  i - OFF_BO, mode);
    else if (i < OFF_BF2) v = cvld(bf1, i - OFF_BF1, mode);
    else if (i < OFF_G1)  v = cvld(bf2, i - OFF_BF2, mode);
    else if (i < OFF_B1N) v = cvld(g1,  i - OFF_G1, mode);
    else if (i < OFF_G2)  v = cvld(b1n, i - OFF_B1N, mode);
    else if (i < OFF_B2N) v = cvld(g2,  i - OFF_G2, mode);
    else if (i < OFF_WHD) v = cvld(b2n, i - OFF_B2N, mode);
    else if (i < OFF_BHD) v = cvld(whd, i - OFF_WHD, mode);
    else                  v = cvld(bhd, i - OFF_BHD, mode);
    A[i] = v;
}

// combined QKV+head bias: bqkvh[z*1024+n] = sum_d b_z[d]*WhT[n,d] + bh[l,n]
__global__ __launch_bounds__(256)
void bias_combine(const u16* __restrict__ arena, const u16* __restrict__ WhT,
                  int l, u16* __restrict__ bqkvh)
{
    int i = blockIdx.x * 256 + threadIdx.x;   // < 3072
    int z = i >> 10, n = i & 1023;
    const u16* bz = arena + OFF_BQKV + l * 3072 + z * 1024;
    const u16* wr = WhT + (long)n * 1024;
    float s = bf2f(arena[OFF_BH + l * 1024 + n]);
    for (int d = 0; d < 1024; d += 8){
        bf16x8 w = *(const bf16x8*)(wr + d);
        bf16x8 b = *(const bf16x8*)(bz + d);
#pragma unroll
        for (int j = 0; j < 8; j++) s += (float)w[j] * (float)b[j];
    }
    bqkvh[i] = f2bf(s);
}

__device__ __forceinline__ float blockSum(float v, float* red){
    int lane = threadIdx.x & 63, wid = threadIdx.x >> 6;
#pragma unroll
    for (int o = 32; o > 0; o >>= 1) v += __shfl_down(v, o, 64);
    __syncthreads();
    if (lane == 0) red[wid] = v;
    __syncthreads();
    return red[0] + red[1] + red[2] + red[3];
}

// h = LN(h + bias + sum_{sp<nparts} bf16 parts[sp]) * g + b
__global__ __launch_bounds__(256)
void ln_fused(float* __restrict__ h, const u16* __restrict__ parts, long pStride,
              int nparts, const u16* __restrict__ bias, u16* __restrict__ hbf,
              const u16* __restrict__ g, const u16* __restrict__ b)
{
    __shared__ float red[4];
    long base = (long)blockIdx.x * DMODEL;
    int tid = threadIdx.x;
    float v[4];
    float s = 0.f;
#pragma unroll
    for (int j = 0; j < 4; j++){
        int c = tid + j * 256;
        float x = bf2f(bias[c]);
        for (int sp = 0; sp < nparts; sp++) x += bf2f(parts[(long)sp * pStride + base + c]);
        float r = h[base + c] + x;
        v[j] = r; s += r;
    }
    float mu = blockSum(s, red) * (1.f / DMODEL);
    float s2 = 0.f;
#pragma unroll
    for (int j = 0; j < 4; j++){ float d = v[j] - mu; s2 += d * d; }
    float var = blockSum(s2, red) * (1.f / DMODEL);
    float inv = rsqrtf(var + 1e-5f);
#pragma unroll
    for (int j = 0; j < 4; j++){
        int c = tid + j * 256;
        float y = (v[j] - mu) * inv * bf2f(g[c]) + bf2f(b[c]);
        h[base + c]   = y;
        hbf[base + c] = f2bf(y);
    }
}

__global__ __launch_bounds__(256)
void head_kernel(const int* __restrict__ flag, const float* __restrict__ h,
                 const u16* __restrict__ arena, const int* __restrict__ nePtr,
                 const int* __restrict__ naPtr, void* __restrict__ outp)
{
    __shared__ float red[4];
    int o = blockIdx.x;
    int ne = *nePtr, na = *naPtr;
    int widx, row;
    if (o < 3 * na){ widx = o / na; row = ne + o % na; }
    else           { widx = 3;      row = o - 3 * na; }
    int tid = threadIdx.x;
    const float* hr = h + (long)row * DMODEL;
    const u16*   w  = arena + OFF_WHD + widx * DMODEL;
    float s = 0.f;
#pragma unroll
    for (int j = 0; j < 4; j++){ int c = tid + j * 256; s += hr[c] * bf2f(w[c]); }
    s = blockSum(s, red);
    if (tid == 0){
        float r = s + bf2f(arena[OFF_BHD + widx]);
        if (*flag) ((float*)outp)[o] = r;
        else       ((u16*)outp)[o]   = f2bf(r);
    }
}

// ---------------------------------------------------------------------------
extern "C" void kernel_launch(void* const* d_in, const int* in_sizes, int n_in,
                              void* d_out, int out_size, void* d_ws, size_t ws_size,
                              hipStream_t stream)
{
    const void* hidden = d_in[0];
    const void* Wq  = d_in[1];  const void* bq  = d_in[2];
    const void* Wk  = d_in[3];  const void* bk  = d_in[4];
    const void* Wv  = d_in[5];  const void* bv  = d_in[6];
    const void* Wh  = d_in[7];  const void* bh  = d_in[8];
    const void* Wo  = d_in[9];  const void* bo  = d_in[10];
    const void* g1  = d_in[11]; const void* b1n = d_in[12];
    const void* g2  = d_in[13]; const void* b2n = d_in[14];
    const void* Wf1 = d_in[15]; const void* bf1 = d_in[16];
    const void* Wf2 = d_in[17]; const void* bf2 = d_in[18];
    const void* Whd = d_in[19]; const void* bhd = d_in[20];
    const int* nePtr = (const int*)d_in[21];
    const int* naPtr = (const int*)d_in[22];

    const long D = 1024, S = 3072, L = 4;

    char* ws = (char*)d_ws;
    size_t off = 0;
    auto alloc = [&](size_t bytes)->char*{
        char* p = ws + off;
        off = (off + bytes + 255) & ~(size_t)255;
        return p;
    };
    int*  flag   = (int*)alloc(256);
    u16*  barena = (u16*)alloc(BIAS_TOT * 2);
    u16*  bqkvh  = (u16*)alloc(3 * D * 2);
    float* rowSums = (float*)alloc(4 * S * 4);     // legacy (wprep zeroes it)
    u16*  WhT    = (u16*)alloc(D * D * 2);
    u16*  WqkvhT = (u16*)alloc(3 * D * D * 2);     // combined (Wz@Wh)^T (3072x1024)
    u16*  WoT    = (u16*)alloc(D * D * 2);
    u16*  Wf1T   = (u16*)alloc(2 * D * D * 2);
    u16*  Wf2T   = (u16*)alloc(2 * D * D * 2);
    float* h     = (float*)alloc(S * D * 4);
    u16*  hbf    = (u16*)alloc(S * D * 2);
    u16*  qkvh   = (u16*)alloc(3 * S * D * 2);     // [Qh;Kh;V^T] (slab 2 = V^T e x s)
    u16*  ctx    = (u16*)alloc(S * D * 2);

    // regionB: ffn1 (S x 2D) + f2Parts (2 x S*D) live concurrently = 37.75 MB.
    // Wcat (prep) and woParts (attn-out) overlap ffn1 space (disjoint lifetimes).
    char* regionB = alloc((size_t)S * 2 * D * 2 + 2 * (size_t)S * D * 2);
    u16* Wcat    = (u16*)regionB;
    u16* woParts = (u16*)regionB;
    u16* ffn1    = (u16*)regionB;
    u16* f2Parts = (u16*)(regionB + (size_t)S * 2 * D * 2);

    const long pSD = S * D;                        // elements per bf16 partial slab

    dim3 tb(32, 8);
    sniff_kernel<<<1, 256, 0, stream>>>((const u16*)hidden, flag);
    cvt_biases<<<(BIAS_TOT + 255) / 256, 256, 0, stream>>>(
        flag, bq, bk, bv, bh, bo, bf1, bf2, g1, b1n, g2, b2n, Whd, bhd, barena);
    init_h<<<(int)(S * D / 256), 256, 0, stream>>>(flag, hidden, h, hbf);

    for (int l = 0; l < L; ++l){
        // ---- prep: transposes + Wcat copy (1 launch) ----
        wprep<<<7728, tb, 0, stream>>>(flag, l, Wo, Wf1, Wf2, Wh, Wq, Wk, Wv,
                                       WoT, Wf1T, Wf2T, WhT, Wcat, rowSums);
        gemm128<1, 0><<<dim3(8, 8, 3), 256, 0, stream>>>(
            WhT, 1024, Wcat, 1024, WqkvhT, 1024, nullptr,
            1024, 0, (long)D * D, (long)D * D, 0, nullptr);
        bias_combine<<<12, 256, 0, stream>>>(barena, WhT, l, bqkvh);

        // ---- fused QKV+head projection; V written transposed into slab 2 ----
        gemm128<1, 1><<<dim3(24, 24, 1), 256, 0, stream>>>(
            hbf, 1024, WqkvhT, 1024, qkvh, 0, bqkvh,
            1024, 0, 0, 0, 0, nullptr);

        // ---- fused attention: QK^T -> exp -> PV -> /rowsum, no S x S buffer ----
        fused_attn<<<dim3(96, 4), 256, 0, stream>>>(qkvh, ctx);

        // ---- attn_out: split-2 bf16 partials; reduce fused into LN ----
        gemm128<2, 0><<<dim3(24, 8, 2), 256, 0, stream>>>(
            ctx, 1024, WoT, 1024, woParts, 1024, nullptr,
            1024, 0, 0, 0, pSD, nullptr);
        ln_fused<<<3072, 256, 0, stream>>>(h, woParts, pSD, 2, barena + OFF_BO + l * D,
                                           hbf, barena + OFF_G1 + l * D, barena + OFF_B1N + l * D);
        // ---- FFN1: single gemm128, bias+ReLU fused ----
        gemm128<1, 2><<<dim3(24, 16, 1), 256, 0, stream>>>(
            hbf, 1024, Wf1T, 1024, ffn1, 2048, barena + OFF_BF1 + l * 2 * D,
            1024, 0, 0, 0, 0, nullptr);
        // ---- FFN2: split-2 bf16 partials; reduce fused into LN ----
        gemm128<2, 0><<<dim3(24, 8, 2), 256, 0, stream>>>(
            ffn1, 2048, Wf2T, 2048, f2Parts, 1024, nullptr,
            2048, 0, 0, 0, pSD, nullptr);
        ln_fused<<<3072, 256, 0, stream>>>(h, f2Parts, pSD, 2, barena + OFF_BF2 + l * D,
                                           hbf, barena + OFF_G2 + l * D, barena + OFF_B2N + l * D);
    }
    head_kernel<<<out_size, 256, 0, stream>>>(flag, h, barena, nePtr, naPtr, d_out);
}

// Round 8
// 1250.541 us; speedup vs baseline: 1.1076x; 1.1076x over previous
//
#include <hip/hip_runtime.h>
#include <cstdint>

typedef unsigned short u16;
typedef __bf16  bf16x8 __attribute__((ext_vector_type(8)));
typedef float   f32x4  __attribute__((ext_vector_type(4)));
typedef unsigned short u16x4 __attribute__((ext_vector_type(4)));
typedef unsigned short u16x8 __attribute__((ext_vector_type(8)));

#define S_LEN 3072
#define DMODEL 1024

__device__ __forceinline__ float bf2f(u16 u){ return __uint_as_float(((unsigned)u) << 16); }
__device__ __forceinline__ u16 f2bf(float f){
    unsigned u = __float_as_uint(f);
    return (u16)((u + 0x7fffu + ((u >> 16) & 1u)) >> 16);
}
// mode-aware element fetch -> bf16 bits (mode 0: bf16 input; mode 1: fp32 input)
__device__ __forceinline__ u16 cvld(const void* p, long i, int mode){
    return mode ? f2bf(((const float*)p)[i]) : ((const u16*)p)[i];
}

__device__ __forceinline__ void async16(const void* g, void* l){
    __builtin_amdgcn_global_load_lds(
        (const __attribute__((address_space(1))) unsigned int*)g,
        (__attribute__((address_space(3))) unsigned int*)l, 16, 0, 0);
}

// ---------------------------------------------------------------------------
// dtype sniffer (proven): flag[0]=1 if inputs are fp32, 0 if bf16; flag[1]=0.
// ---------------------------------------------------------------------------
__global__ void sniff_kernel(const u16* __restrict__ x, int* __restrict__ flag)
{
    __shared__ int r[256];
    int tid = threadIdx.x, w = 0;
    for (int j = tid; j < 4096; j += 256){
        int e = (x[j] >> 7) & 0xFF;
        if (e < 90 || e > 140) w++;
    }
    r[tid] = w; __syncthreads();
    for (int s = 128; s > 0; s >>= 1){ if (tid < s) r[tid] += r[tid + s]; __syncthreads(); }
    if (tid == 0){ flag[0] = (r[0] > 256) ? 1 : 0; flag[1] = 0; }
}

// ---------------------------------------------------------------------------
// LDS swizzle note (all MFMA kernels): logical (row m, 16B-chunk c) lives at
// physical chunk c ^ (m&7).  global_load_lds dest stays LINEAR (HW rule); the
// XOR is applied to the per-thread GLOBAL source chunk.  Reads use
// j = c ^ (lr&7) (fragment row ≡ lr mod 8) -> 2-way (free) bank access.
// ---------------------------------------------------------------------------

// ---------------------------------------------------------------------------
// FUSED ATTENTION v2 (max-free softmax; no rescaling needed).
// R7 fix: SINGLE-buffered K+V (69 KB LDS -> 2 blocks/CU, latency hidden by
// co-resident block; K/V have no cross-wave reuse so dbuf only cost LDS) and
// P row stride 64->72 u16 (rows were 128 B apart = all bank 0 -> 2.4M
// conflicts; 144 B offsets rows by 4 banks, keeps 16 B alignment).
// Per iter: [free-bar] stage(it) [drain-bar] QK^T -> exp/P [P-bar] PV.
// LDS: K 32K | V 32K | P 4.5K | rs 0.5K = 69 KB.
// ---------------------------------------------------------------------------
#define PSTR 72
__global__ __launch_bounds__(256)
void fused_attn(const u16* __restrict__ qkvh, u16* __restrict__ ctx)
{
    __shared__ __align__(16) u16 smem[35328];      // 69 KB
    u16*  Kd  = smem;                              // [64 kv][256 e] swizzled
    u16*  Vd  = smem + 16384;                      // [256 e][64 kv] swizzled
    u16*  Pb  = smem + 32768;                      // [32 q][PSTR]   swizzled
    float* rsb = (float*)(smem + 32768 + 32 * PSTR); // [4 waves][32 rows]

    const int tid  = threadIdx.x;
    const int lane = tid & 63, wid = tid >> 6;
    const int quad = lane >> 4, lr = lane & 15;
    const int jx = lr & 7;
    const int h = blockIdx.y;
    const int qbase = blockIdx.x * 32;

    const u16* Q  = qkvh + (long)qbase * DMODEL + h * 256;
    const u16* K  = qkvh + (long)S_LEN * DMODEL + h * 256;                    // [s][e]
    const u16* Vt = qkvh + (long)2 * S_LEN * DMODEL + (long)h * 256 * S_LEN;  // [e][s]

    // Q fragments in registers: row mt*16+lr, e-chunk (ks*4+quad)
    bf16x8 qf[2][8];
#pragma unroll
    for (int mt = 0; mt < 2; ++mt)
#pragma unroll
        for (int ks = 0; ks < 8; ++ks)
            qf[mt][ks] = *(const bf16x8*)(Q + (long)(mt*16 + lr) * DMODEL + (ks*4 + quad) * 8);

    f32x4 zero = {0.f, 0.f, 0.f, 0.f};
    f32x4 oa[2][4];
#pragma unroll
    for (int mt = 0; mt < 2; ++mt)
#pragma unroll
        for (int nt = 0; nt < 4; ++nt) oa[mt][nt] = zero;
    float rsp[2][4] = {{0.f,0.f,0.f,0.f},{0.f,0.f,0.f,0.f}};

    // staging maps: K-tile 64(kv)x256(e) = 2048 chunks; V-tile 256(e)x64(kv)
    const u16* kP[8]; const u16* vP[8]; int dOf[8];
#pragma unroll
    for (int i = 0; i < 8; ++i){
        int u = i * 256 + tid;
        int kr = u >> 5, kc = u & 31;
        kP[i] = K + (long)kr * DMODEL + (kc ^ (kr & 7)) * 8;
        int vr = u >> 3, vc = u & 7;
        vP[i] = Vt + (long)vr * S_LEN + (vc ^ (vr & 7)) * 8;
        dOf[i] = u * 8;
    }

    auto stageKV = [&](int it){
        const int kv0 = it << 6;
#pragma unroll
        for (int i = 0; i < 8; ++i) async16(kP[i] + (long)kv0 * DMODEL, Kd + dOf[i]);
#pragma unroll
        for (int i = 0; i < 8; ++i) async16(vP[i] + kv0, Vd + dOf[i]);
    };

    const float scale = 0.0625f;                  // 1/sqrt(256)
    for (int it = 0; it < 48; ++it){
        __syncthreads();        // all waves done with K/V of prev iter
        stageKV(it);
        __syncthreads();        // drain: K/V ready (vmcnt 0 at barrier)
        // ---- QK^T: S[32 q][16 kv] per wave (kv cols wid*16..) ----
        f32x4 sa0 = zero, sa1 = zero;
#pragma unroll
        for (int ks = 0; ks < 8; ++ks){
            const int j = (ks*4 + quad) ^ jx;
            bf16x8 kb = *(const bf16x8*)(Kd + (wid*16 + lr) * 256 + j*8);
            sa0 = __builtin_amdgcn_mfma_f32_16x16x32_bf16(qf[0][ks], kb, sa0, 0, 0, 0);
            sa1 = __builtin_amdgcn_mfma_f32_16x16x32_bf16(qf[1][ks], kb, sa1, 0, 0, 0);
        }
        // ---- exp + rowsum partials + swizzled P write (stride PSTR) ----
#pragma unroll
        for (int mt = 0; mt < 2; ++mt){
#pragma unroll
            for (int r = 0; r < 4; ++r){
                float e = __expf((mt ? sa1[r] : sa0[r]) * scale);   // |arg|<~2
                rsp[mt][r] += e;
                int m = mt*16 + quad*4 + r;
                Pb[m*PSTR + (((wid*2 + (lr >> 3)) ^ (m & 7)) * 8) + (lr & 7)] = f2bf(e);
            }
        }
        __syncthreads();        // P visible to all waves
        // ---- PV: O[32][64 e] per wave (e cols wid*64..) ----
#pragma unroll
        for (int ks = 0; ks < 2; ++ks){
            const int j = (ks*4 + quad) ^ jx;
            bf16x8 pa0 = *(const bf16x8*)(Pb + lr*PSTR        + j*8);
            bf16x8 pa1 = *(const bf16x8*)(Pb + (16 + lr)*PSTR + j*8);
#pragma unroll
            for (int nt = 0; nt < 4; ++nt){
                bf16x8 vb = *(const bf16x8*)(Vd + (wid*64 + nt*16 + lr) * 64 + j*8);
                oa[0][nt] = __builtin_amdgcn_mfma_f32_16x16x32_bf16(pa0, vb, oa[0][nt], 0, 0, 0);
                oa[1][nt] = __builtin_amdgcn_mfma_f32_16x16x32_bf16(pa1, vb, oa[1][nt], 0, 0, 0);
            }
        }
    }

    // ---- rowsums: 16-lane butterfly, cross-wave via LDS ----
#pragma unroll
    for (int mt = 0; mt < 2; ++mt)
#pragma unroll
        for (int r = 0; r < 4; ++r){
            float v = rsp[mt][r];
            v += __shfl_xor(v, 1, 64);
            v += __shfl_xor(v, 2, 64);
            v += __shfl_xor(v, 4, 64);
            v += __shfl_xor(v, 8, 64);
            if (lr == 0) rsb[wid*32 + mt*16 + quad*4 + r] = v;
        }
    __syncthreads();
    float inv[2][4];
#pragma unroll
    for (int mt = 0; mt < 2; ++mt)
#pragma unroll
        for (int r = 0; r < 4; ++r){
            int m = mt*16 + quad*4 + r;
            inv[mt][r] = 1.f / (rsb[m] + rsb[32 + m] + rsb[64 + m] + rsb[96 + m]);
        }
    __syncthreads();            // everyone has inv; K region reusable as scratch

    // ---- epilogue: O * inv -> wave-private u16 repack -> coalesced store ----
    u16* scw = smem + (size_t)wid * (16 * 72);     // inside dead K region
    const int row_l = lane >> 2, cq = lane & 3;
#pragma unroll
    for (int mt = 0; mt < 2; ++mt){
#pragma unroll
        for (int nt = 0; nt < 4; ++nt)
#pragma unroll
            for (int r = 0; r < 4; ++r)
                scw[(quad*4 + r) * 72 + nt*16 + lr] = f2bf(oa[mt][nt][r] * inv[mt][r]);
        u16x8 p0 = *(const u16x8*)(scw + row_l * 72 + cq * 16);
        u16x8 p1 = *(const u16x8*)(scw + row_l * 72 + cq * 16 + 8);
        u16* cp = ctx + (long)(qbase + mt*16 + row_l) * DMODEL + h * 256 + wid * 64 + cq * 16;
        *(u16x8*)cp       = p0;
        *(u16x8*)(cp + 8) = p1;
    }
}

// ---------------------------------------------------------------------------
// NT GEMM 128x128 tile, DOUBLE-BUFFERED 2-phase prefetch + swizzled LDS.
// SPLIT>1: bf16 partials at sp*pStride + bat*cBS (pStride in elements).
// SPLIT==1 modes: 0 bf16(+bias), 1 QKV scatter (Q,K natural; V transposed),
//                 2 bias+ReLU.
// Wave layout: 2x2 waves, each owns a 64x64 quadrant (acc[4][4]).
// ---------------------------------------------------------------------------
template<int SPLIT, int MODE>
__global__ __launch_bounds__(256)
void gemm128(const u16* __restrict__ A, int lda,
             const u16* __restrict__ B, int ldb,
             void* __restrict__ Cv, int ldc,
             const u16* __restrict__ bias,
             int K, long aBS, long bBS, long cBS, long pStride,
             const float* __restrict__ rs)
{
    __shared__ __align__(16) u16 smem[4 * 128 * 64];     // 64 KB: 2x(A+B)
    u16* As0 = smem;
    u16* Bs0 = smem + 2 * 128 * 64;
    const int tid  = threadIdx.x;
    const int lane = tid & 63, wid = tid >> 6;
    const int wm = wid >> 1, wn = wid & 1;
    const int quad = lane >> 4, lr = lane & 15;
    const int jx = lr & 7;

    const int z   = blockIdx.z;
    const int bat = z / SPLIT;
    const int sp  = z % SPLIT;
    const int kLen = K / SPLIT;

    A += (long)bat * aBS + (long)blockIdx.x * 128 * lda + (long)sp * kLen;
    B += (long)bat * bBS + (long)blockIdx.y * 128 * ldb + (long)sp * kLen;

    f32x4 zero = {0.f, 0.f, 0.f, 0.f};
    f32x4 acc[4][4];
#pragma unroll
    for (int i = 0; i < 4; i++)
#pragma unroll
        for (int j = 0; j < 4; j++) acc[i][j] = zero;

    const u16* aP[4]; const u16* bP[4]; int ldst[4];
#pragma unroll
    for (int i = 0; i < 4; i++){
        int u = i * 256 + tid;
        int m = u >> 3, c = u & 7;
        int cs = c ^ (m & 7);                 // pre-swizzled global chunk
        aP[i] = A + (long)m * lda + cs * 8;
        bP[i] = B + (long)m * ldb + cs * 8;
        ldst[i] = u * 8;
    }

    auto stage = [&](int kt, int b){
        const int k0 = kt << 6;
        u16* Ad = As0 + b * (128 * 64);
        u16* Bd = Bs0 + b * (128 * 64);
#pragma unroll
        for (int i = 0; i < 4; i++) async16(aP[i] + k0, Ad + ldst[i]);
#pragma unroll
        for (int i = 0; i < 4; i++) async16(bP[i] + k0, Bd + ldst[i]);
    };

    const int kTiles = kLen >> 6;
    stage(0, 0);
    __syncthreads();                       // drains prologue loads (vmcnt 0)
    for (int kt = 0; kt < kTiles; ++kt){
        const int cur = kt & 1;
        if (kt + 1 < kTiles) stage(kt + 1, cur ^ 1);   // prefetch next tile
        const u16* Ac = As0 + cur * (128 * 64);
        const u16* Bc = Bs0 + cur * (128 * 64);
#pragma unroll
        for (int ks = 0; ks < 2; ++ks){
            const int j = (ks * 4 + quad) ^ jx;
            bf16x8 af[4], bfg[4];
#pragma unroll
            for (int t = 0; t < 4; t++){
                int m  = wm * 64 + t * 16 + lr;
                af[t]  = *(const bf16x8*)(Ac + (m * 8 + j) * 8);
                int n  = wn * 64 + t * 16 + lr;
                bfg[t] = *(const bf16x8*)(Bc + (n * 8 + j) * 8);
            }
#pragma unroll
            for (int mt = 0; mt < 4; mt++)
#pragma unroll
                for (int nt = 0; nt < 4; nt++)
                    acc[mt][nt] = __builtin_amdgcn_mfma_f32_16x16x32_bf16(
                        af[mt], bfg[nt], acc[mt][nt], 0, 0, 0);
        }
        __syncthreads();   // all waves done with buf[cur]; prefetch drained
    }

    const int rowBase = blockIdx.x * 128 + wm * 64;
    const int colBase = blockIdx.y * 128 + wn * 64;
    const int slabw = colBase >> 10;             // wave-uniform (128 | 1024)

    if (MODE == 1 && slabw == 2){
        // ---- V^T path: bias, per-16-col transpose in LDS (u16, stride 72),
        //      store along s.  Wave-private scratch: 16x72 u16 = 2304 B. ----
        u16* scw = smem + (size_t)wid * (16 * 72);
        const int e_l = lane >> 2, sh = lane & 3;
#pragma unroll
        for (int nt = 0; nt < 4; nt++){
            float bv2 = bf2f(bias[colBase + nt * 16 + lr]);
#pragma unroll
            for (int mt = 0; mt < 4; mt++){
                u16x4 pk;
#pragma unroll
                for (int r = 0; r < 4; r++) pk[r] = f2bf(acc[mt][nt][r] + bv2);
                *(u16x4*)(scw + lr * 72 + mt * 16 + quad * 4) = pk;
            }
            const int e_g = (colBase & 1023) + nt * 16 + e_l;
            u16* dst = (u16*)Cv + (long)2 * S_LEN * DMODEL + (long)e_g * S_LEN
                     + rowBase + sh * 16;
            *(u16x8*)(dst)     = *(const u16x8*)(scw + e_l * 72 + sh * 16);
            *(u16x8*)(dst + 8) = *(const u16x8*)(scw + e_l * 72 + sh * 16 + 8);
        }
        return;
    }

    // ---- generic path: per-mt wave-private fp32 repack, coalesced stores ----
    float* scw = (float*)smem + (size_t)wid * (16 * 68);   // 4352 B / wave
    const int row_l = lane >> 2, cq = lane & 3;
#pragma unroll
    for (int mt = 0; mt < 4; ++mt){
#pragma unroll
        for (int nt = 0; nt < 4; nt++)
#pragma unroll
            for (int r = 0; r < 4; r++)
                scw[(quad * 4 + r) * 68 + nt * 16 + lr] = acc[mt][nt][r];
        float vals[16];
#pragma unroll
        for (int j = 0; j < 4; j++)
            *(f32x4*)(vals + j * 4) = *(const f32x4*)(scw + row_l * 68 + cq * 16 + j * 4);
        const int row_g = rowBase + mt * 16 + row_l;
        const int colg  = colBase + cq * 16;
        float bv[16];
        if (SPLIT == 1 && bias){
            u16x8 b0 = *(const u16x8*)(bias + colg);
            u16x8 b1 = *(const u16x8*)(bias + colg + 8);
#pragma unroll
            for (int i = 0; i < 8; i++){ bv[i] = bf2f(b0[i]); bv[8 + i] = bf2f(b1[i]); }
        } else {
#pragma unroll
            for (int i = 0; i < 16; i++) bv[i] = 0.f;
        }
        u16x8 pk0, pk1;
#pragma unroll
        for (int i = 0; i < 16; i++){
            float v = vals[i] + bv[i];
            if (MODE == 2) v = fmaxf(v, 0.f);
            if (i < 8) pk0[i] = f2bf(v); else pk1[i - 8] = f2bf(v);
        }
        long idx;
        if (SPLIT > 1)      idx = (long)sp * pStride + (long)bat * cBS + (long)row_g * ldc + colg;
        else if (MODE == 1) idx = ((long)slabw * S_LEN + row_g) * DMODEL + (colg & 1023);
        else                idx = (long)bat * cBS + (long)row_g * ldc + colg;
        u16* cp = (u16*)Cv + idx;
        *(u16x8*)cp       = pk0;
        *(u16x8*)(cp + 8) = pk1;
    }
}

// ---------------------------------------------------------------------------
// merged per-layer prep: weight transposes + Wq|Wk|Wv copy + rowSums zero.
// grid.x = 7728, block (32,8).
// ---------------------------------------------------------------------------
__global__ __launch_bounds__(256)
void wprep(const int* __restrict__ flag, int l,
           const void* Wo, const void* Wf1, const void* Wf2, const void* Wh,
           const void* Wq, const void* Wk, const void* Wv,
           u16* __restrict__ WoT, u16* __restrict__ Wf1T,
           u16* __restrict__ Wf2T, u16* __restrict__ WhT,
           u16* __restrict__ Wcat, float* __restrict__ rowSums)
{
    const int mode = *flag;
    const int z = blockIdx.x;
    const int tx = threadIdx.x, ty = threadIdx.y;

    if (z >= 7680){
        int idx = (z - 7680) * 256 + ty * 32 + tx;   // < 12288
        rowSums[idx] = 0.f;
        return;
    }
    if (z >= 6144){
        int t = ty * 32 + tx;
        long base = (long)(z - 6144) * 2048;
#pragma unroll
        for (int j = 0; j < 8; j++){
            long g = base + j * 256 + t;
            int slab = (int)(g >> 20);
            long r = g & 1048575;
            const void* src = (slab == 0) ? Wq : (slab == 1) ? Wk : Wv;
            Wcat[g] = cvld(src, (long)l * 1048576 + r, mode);
        }
        return;
    }

    const void* in; u16* out; long ib; int R, C, rb, cb;
    if (z < 1024){
        in = Wo; out = WoT; ib = (long)l * 1048576; R = 1024; C = 1024;
        cb = z & 31; rb = z >> 5;
    } else if (z < 3072){
        int t = z - 1024;
        in = Wf1; out = Wf1T; ib = (long)l * 2097152; R = 1024; C = 2048;
        cb = t & 63; rb = t >> 6;
    } else if (z < 5120){
        int t = z - 3072;
        in = Wf2; out = Wf2T; ib = (long)l * 2097152; R = 2048; C = 1024;
        cb = t & 31; rb = t >> 5;
    } else {
        int t = z - 5120;
        int a = t >> 8, u = t & 255;
        in = Wh; out = WhT + (long)a * 262144;
        ib = (long)l * 1048576 + (long)a * 262144; R = 1024; C = 256;
        cb = u & 7; rb = u >> 3;
    }

    __shared__ u16 tbuf[32][34];
    int r0 = rb * 32, c0 = cb * 32;
#pragma unroll
    for (int j = 0; j < 4; j++){
        int r = r0 + ty + j * 8;
        tbuf[ty + j * 8][tx] = cvld(in, ib + (long)r * C + c0 + tx, mode);
    }
    __syncthreads();
#pragma unroll
    for (int j = 0; j < 4; j++){
        int c = c0 + ty + j * 8;
        out[(long)c * R + r0 + tx] = tbuf[tx][ty + j * 8];
    }
}

__global__ __launch_bounds__(256)
void init_h(const int* __restrict__ flag, const void* __restrict__ hin,
            float* __restrict__ h, u16* __restrict__ hbf)
{
    const int mode = *flag;
    long i = (long)blockIdx.x * 256 + threadIdx.x;
    u16 u = cvld(hin, i, mode);
    h[i]   = bf2f(u);
    hbf[i] = u;
}

// bias arena layout (elements)
#define OFF_BQKV 0
#define OFF_BH   12288
#define OFF_BO   16384
#define OFF_BF1  20480
#define OFF_BF2  28672
#define OFF_G1   32768
#define OFF_B1N  36864
#define OFF_G2   40960
#define OFF_B2N  45056
#define OFF_WHD  49152
#define OFF_BHD  53248
#define BIAS_TOT 53252

__global__ __launch_bounds__(256)
void cvt_biases(const int* __restrict__ flag,
                const void* bq, const void* bk, const void* bv, const void* bh,
                const void* bo, const void* bf1, const void* bf2,
                const void* g1, const void* b1n, const void* g2, const void* b2n,
                const void* whd, const void* bhd, u16* __restrict__ A)
{
    int i = blockIdx.x * 256 + threadIdx.x;
    if (i >= BIAS_TOT) return;
    const int mode = *flag;
    u16 v;
    if (i < OFF_BH){
        int l = i / 3072, r = i % 3072;
        const void* p = (r < 1024) ? bq : (r < 2048) ? bk : bv;
        v = cvld(p, (long)l * 1024 + (r & 1023), mode);
    }
    else if (i < OFF_BO)  v = cvld(bh,  i - OFF_BH, mode);
    else if (i < OFF_BF1) v = cvld(bo,  i - OFF_BO, mode);
    else if (i < OFF_BF2) v = cvld(bf1, i - OFF_BF1, mode);
    else if (i < OFF_G1)  v = cvld(bf2, i - OFF_BF2, mode);
    else if (i < OFF_B1N) v = cvld(g1,  i - OFF_G1, mode);
    else if (i < OFF_G2)  v = cvld(b1n, i - OFF_B1N, mode);
    else if (i < OFF_B2N) v = cvld(g2,  i - OFF_G2, mode);
    else if (i < OFF_WHD) v = cvld(b2n, i - OFF_B2N, mode);
    else if (i < OFF_BHD) v = cvld(whd, i - OFF_WHD, mode);
    else                  v = cvld(bhd, i - OFF_BHD, mode);
    A[i] = v;
}

// combined QKV+head bias: bqkvh[z*1024+n] = sum_d b_z[d]*WhT[n,d] + bh[l,n]
__global__ __launch_bounds__(256)
void bias_combine(const u16* __restrict__ arena, const u16* __restrict__ WhT,
                  int l, u16* __restrict__ bqkvh)
{
    int i = blockIdx.x * 256 + threadIdx.x;   // < 3072
    int z = i >> 10, n = i & 1023;
    const u16* bz = arena + OFF_BQKV + l * 3072 + z * 1024;
    const u16* wr = WhT + (long)n * 1024;
    float s = bf2f(arena[OFF_BH + l * 1024 + n]);
    for (int d = 0; d < 1024; d += 8){
        bf16x8 w = *(const bf16x8*)(wr + d);
        bf16x8 b = *(const bf16x8*)(bz + d);
#pragma unroll
        for (int j = 0; j < 8; j++) s += (float)w[j] * (float)b[j];
    }
    bqkvh[i] = f2bf(s);
}

__device__ __forceinline__ float blockSum(float v, float* red){
    int lane = threadIdx.x & 63, wid = threadIdx.x >> 6;
#pragma unroll
    for (int o = 32; o > 0; o >>= 1) v += __shfl_down(v, o, 64);
    __syncthreads();
    if (lane == 0) red[wid] = v;
    __syncthreads();
    return red[0] + red[1] + red[2] + red[3];
}

// h = LN(h + bias + sum_{sp<nparts} bf16 parts[sp]) * g + b
__global__ __launch_bounds__(256)
void ln_fused(float* __restrict__ h, const u16* __restrict__ parts, long pStride,
              int nparts, const u16* __restrict__ bias, u16* __restrict__ hbf,
              const u16* __restrict__ g, const u16* __restrict__ b)
{
    __shared__ float red[4];
    long base = (long)blockIdx.x * DMODEL;
    int tid = threadIdx.x;
    float v[4];
    float s = 0.f;
#pragma unroll
    for (int j = 0; j < 4; j++){
        int c = tid + j * 256;
        float x = bf2f(bias[c]);
        for (int sp = 0; sp < nparts; sp++) x += bf2f(parts[(long)sp * pStride + base + c]);
        float r = h[base + c] + x;
        v[j] = r; s += r;
    }
    float mu = blockSum(s, red) * (1.f / DMODEL);
    float s2 = 0.f;
#pragma unroll
    for (int j = 0; j < 4; j++){ float d = v[j] - mu; s2 += d * d; }
    float var = blockSum(s2, red) * (1.f / DMODEL);
    float inv = rsqrtf(var + 1e-5f);
#pragma unroll
    for (int j = 0; j < 4; j++){
        int c = tid + j * 256;
        float y = (v[j] - mu) * inv * bf2f(g[c]) + bf2f(b[c]);
        h[base + c]   = y;
        hbf[base + c] = f2bf(y);
    }
}

__global__ __launch_bounds__(256)
void head_kernel(const int* __restrict__ flag, const float* __restrict__ h,
                 const u16* __restrict__ arena, const int* __restrict__ nePtr,
                 const int* __restrict__ naPtr, void* __restrict__ outp)
{
    __shared__ float red[4];
    int o = blockIdx.x;
    int ne = *nePtr, na = *naPtr;
    int widx, row;
    if (o < 3 * na){ widx = o / na; row = ne + o % na; }
    else           { widx = 3;      row = o - 3 * na; }
    int tid = threadIdx.x;
    const float* hr = h + (long)row * DMODEL;
    const u16*   w  = arena + OFF_WHD + widx * DMODEL;
    float s = 0.f;
#pragma unroll
    for (int j = 0; j < 4; j++){ int c = tid + j * 256; s += hr[c] * bf2f(w[c]); }
    s = blockSum(s, red);
    if (tid == 0){
        float r = s + bf2f(arena[OFF_BHD + widx]);
        if (*flag) ((float*)outp)[o] = r;
        else       ((u16*)outp)[o]   = f2bf(r);
    }
}

// ---------------------------------------------------------------------------
extern "C" void kernel_launch(void* const* d_in, const int* in_sizes, int n_in,
                              void* d_out, int out_size, void* d_ws, size_t ws_size,
                              hipStream_t stream)
{
    const void* hidden = d_in[0];
    const void* Wq  = d_in[1];  const void* bq  = d_in[2];
    const void* Wk  = d_in[3];  const void* bk  = d_in[4];
    const void* Wv  = d_in[5];  const void* bv  = d_in[6];
    const void* Wh  = d_in[7];  const void* bh  = d_in[8];
    const void* Wo  = d_in[9];  const void* bo  = d_in[10];
    const void* g1  = d_in[11]; const void* b1n = d_in[12];
    const void* g2  = d_in[13]; const void* b2n = d_in[14];
    const void* Wf1 = d_in[15]; const void* bf1 = d_in[16];
    const void* Wf2 = d_in[17]; const void* bf2 = d_in[18];
    const void* Whd = d_in[19]; const void* bhd = d_in[20];
    const int* nePtr = (const int*)d_in[21];
    const int* naPtr = (const int*)d_in[22];

    const long D = 1024, S = 3072, L = 4;

    char* ws = (char*)d_ws;
    size_t off = 0;
    auto alloc = [&](size_t bytes)->char*{
        char* p = ws + off;
        off = (off + bytes + 255) & ~(size_t)255;
        return p;
    };
    int*  flag   = (int*)alloc(256);
    u16*  barena = (u16*)alloc(BIAS_TOT * 2);
    u16*  bqkvh  = (u16*)alloc(3 * D * 2);
    float* rowSums = (float*)alloc(4 * S * 4);     // legacy (wprep zeroes it)
    u16*  WhT    = (u16*)alloc(D * D * 2);
    u16*  WqkvhT = (u16*)alloc(3 * D * D * 2);     // combined (Wz@Wh)^T (3072x1024)
    u16*  WoT    = (u16*)alloc(D * D * 2);
    u16*  Wf1T   = (u16*)alloc(2 * D * D * 2);
    u16*  Wf2T   = (u16*)alloc(2 * D * D * 2);
    float* h     = (float*)alloc(S * D * 4);
    u16*  hbf    = (u16*)alloc(S * D * 2);
    u16*  qkvh   = (u16*)alloc(3 * S * D * 2);     // [Qh;Kh;V^T] (slab 2 = V^T e x s)
    u16*  ctx    = (u16*)alloc(S * D * 2);

    // regionB: ffn1 (S x 2D) + f2Parts (2 x S*D) live concurrently = 37.75 MB.
    // Wcat (prep) and woParts (attn-out) overlap ffn1 space (disjoint lifetimes).
    char* regionB = alloc((size_t)S * 2 * D * 2 + 2 * (size_t)S * D * 2);
    u16* Wcat    = (u16*)regionB;
    u16* woParts = (u16*)regionB;
    u16* ffn1    = (u16*)regionB;
    u16* f2Parts = (u16*)(regionB + (size_t)S * 2 * D * 2);

    const long pSD = S * D;                        // elements per bf16 partial slab

    dim3 tb(32, 8);
    sniff_kernel<<<1, 256, 0, stream>>>((const u16*)hidden, flag);
    cvt_biases<<<(BIAS_TOT + 255) / 256, 256, 0, stream>>>(
        flag, bq, bk, bv, bh, bo, bf1, bf2, g1, b1n, g2, b2n, Whd, bhd, barena);
    init_h<<<(int)(S * D / 256), 256, 0, stream>>>(flag, hidden, h, hbf);

    for (int l = 0; l < L; ++l){
        // ---- prep: transposes + Wcat copy (1 launch) ----
        wprep<<<7728, tb, 0, stream>>>(flag, l, Wo, Wf1, Wf2, Wh, Wq, Wk, Wv,
                                       WoT, Wf1T, Wf2T, WhT, Wcat, rowSums);
        gemm128<1, 0><<<dim3(8, 8, 3), 256, 0, stream>>>(
            WhT, 1024, Wcat, 1024, WqkvhT, 1024, nullptr,
            1024, 0, (long)D * D, (long)D * D, 0, nullptr);
        bias_combine<<<12, 256, 0, stream>>>(barena, WhT, l, bqkvh);

        // ---- fused QKV+head projection; V written transposed into slab 2 ----
        gemm128<1, 1><<<dim3(24, 24, 1), 256, 0, stream>>>(
            hbf, 1024, WqkvhT, 1024, qkvh, 0, bqkvh,
            1024, 0, 0, 0, 0, nullptr);

        // ---- fused attention: QK^T -> exp -> PV -> /rowsum, no S x S buffer ----
        fused_attn<<<dim3(96, 4), 256, 0, stream>>>(qkvh, ctx);

        // ---- attn_out: split-2 bf16 partials; reduce fused into LN ----
        gemm128<2, 0><<<dim3(24, 8, 2), 256, 0, stream>>>(
            ctx, 1024, WoT, 1024, woParts, 1024, nullptr,
            1024, 0, 0, 0, pSD, nullptr);
        ln_fused<<<3072, 256, 0, stream>>>(h, woParts, pSD, 2, barena + OFF_BO + l * D,
                                           hbf, barena + OFF_G1 + l * D, barena + OFF_B1N + l * D);
        // ---- FFN1: single gemm128, bias+ReLU fused ----
        gemm128<1, 2><<<dim3(24, 16, 1), 256, 0, stream>>>(
            hbf, 1024, Wf1T, 1024, ffn1, 2048, barena + OFF_BF1 + l * 2 * D,
            1024, 0, 0, 0, 0, nullptr);
        // ---- FFN2: split-2 bf16 partials; reduce fused into LN ----
        gemm128<2, 0><<<dim3(24, 8, 2), 256, 0, stream>>>(
            ffn1, 2048, Wf2T, 2048, f2Parts, 1024, nullptr,
            2048, 0, 0, 0, pSD, nullptr);
        ln_fused<<<3072, 256, 0, stream>>>(h, f2Parts, pSD, 2, barena + OFF_BF2 + l * D,
                                           hbf, barena + OFF_G2 + l * D, barena + OFF_B2N + l * D);
    }
    head_kernel<<<out_size, 256, 0, stream>>>(flag, h, barena, nePtr, naPtr, d_out);
}

// Round 9
// 1159.871 us; speedup vs baseline: 1.1942x; 1.0782x over previous
//
#include <hip/hip_runtime.h>
#include <cstdint>

typedef unsigned short u16;
typedef __bf16  bf16x8 __attribute__((ext_vector_type(8)));
typedef float   f32x4  __attribute__((ext_vector_type(4)));
typedef unsigned short u16x4 __attribute__((ext_vector_type(4)));
typedef unsigned short u16x8 __attribute__((ext_vector_type(8)));

#define S_LEN 3072
#define DMODEL 1024

__device__ __forceinline__ float bf2f(u16 u){ return __uint_as_float(((unsigned)u) << 16); }
__device__ __forceinline__ u16 f2bf(float f){
    unsigned u = __float_as_uint(f);
    return (u16)((u + 0x7fffu + ((u >> 16) & 1u)) >> 16);
}
// mode-aware element fetch -> bf16 bits (mode 0: bf16 input; mode 1: fp32 input)
__device__ __forceinline__ u16 cvld(const void* p, long i, int mode){
    return mode ? f2bf(((const float*)p)[i]) : ((const u16*)p)[i];
}

__device__ __forceinline__ void async16(const void* g, void* l){
    __builtin_amdgcn_global_load_lds(
        (const __attribute__((address_space(1))) unsigned int*)g,
        (__attribute__((address_space(3))) unsigned int*)l, 16, 0, 0);
}

// ---------------------------------------------------------------------------
// dtype sniffer (proven): flag[0]=1 if inputs are fp32, 0 if bf16; flag[1]=0.
// ---------------------------------------------------------------------------
__global__ void sniff_kernel(const u16* __restrict__ x, int* __restrict__ flag)
{
    __shared__ int r[256];
    int tid = threadIdx.x, w = 0;
    for (int j = tid; j < 4096; j += 256){
        int e = (x[j] >> 7) & 0xFF;
        if (e < 90 || e > 140) w++;
    }
    r[tid] = w; __syncthreads();
    for (int s = 128; s > 0; s >>= 1){ if (tid < s) r[tid] += r[tid + s]; __syncthreads(); }
    if (tid == 0){ flag[0] = (r[0] > 256) ? 1 : 0; flag[1] = 0; }
}

// ---------------------------------------------------------------------------
// LDS swizzle note (both GEMMs): logical (row m, 16B-chunk c) lives at
// physical chunk c ^ (m&7).  global_load_lds dest stays LINEAR (HW rule); the
// XOR is applied to the per-thread GLOBAL source chunk.  Reads use
// j = c ^ (lr&7) (fragment row ≡ lr mod 8) -> 2-way (free) bank access.
// ---------------------------------------------------------------------------

// ---------------------------------------------------------------------------
// Scores GEMM 128x128: SINGLE-buffered staging (32 KB LDS; 2304-block grid is
// TLP-rich, dbuf only cost occupancy — A/B: 49.4 vs 52.8 us) + register
// exp/f2bf/rowsum epilogue (cut VALUBusy 38->30%) with wave-private u16
// repack, barrier-free.
// ---------------------------------------------------------------------------
__global__ __launch_bounds__(256)
void gemm_scores(const u16* __restrict__ A, int lda,
                 const u16* __restrict__ B, int ldb,
                 u16* __restrict__ C, int ldc,
                 float* __restrict__ rowSums,
                 int K, long aBS, long bBS, long cBS)
{
    __shared__ __align__(16) u16 smem[2 * 128 * 64];     // 32 KB
    u16* Abuf = smem;
    u16* Bbuf = smem + 128 * 64;
    const int tid  = threadIdx.x;
    const int lane = tid & 63, wid = tid >> 6;
    const int wm = wid >> 1, wn = wid & 1;
    const int quad = lane >> 4, lr = lane & 15;
    const int jx = lr & 7;
    const int bat = blockIdx.z;

    A += (long)bat * aBS + (long)blockIdx.x * 128 * lda;
    B += (long)bat * bBS + (long)blockIdx.y * 128 * ldb;

    f32x4 zero = {0.f, 0.f, 0.f, 0.f};
    f32x4 acc[4][4];
#pragma unroll
    for (int i = 0; i < 4; i++)
#pragma unroll
        for (int j = 0; j < 4; j++) acc[i][j] = zero;

    const u16* aP[4]; const u16* bP[4]; int ldst[4];
#pragma unroll
    for (int i = 0; i < 4; i++){
        int u = i * 256 + tid;
        int m = u >> 3, c = u & 7;
        int cs = c ^ (m & 7);                 // pre-swizzled global chunk
        aP[i] = A + (long)m * lda + cs * 8;
        bP[i] = B + (long)m * ldb + cs * 8;
        ldst[i] = u * 8;
    }

    const int kTiles = K >> 6;
    for (int kt = 0; kt < kTiles; ++kt){
        const int k0 = kt << 6;
        __syncthreads();
#pragma unroll
        for (int i = 0; i < 4; i++) async16(aP[i] + k0, Abuf + ldst[i]);
#pragma unroll
        for (int i = 0; i < 4; i++) async16(bP[i] + k0, Bbuf + ldst[i]);
        __syncthreads();
#pragma unroll
        for (int ks = 0; ks < 2; ++ks){
            const int j = (ks * 4 + quad) ^ jx;
            bf16x8 af[4], bfg[4];
#pragma unroll
            for (int t = 0; t < 4; t++){
                int m  = wm * 64 + t * 16 + lr;
                af[t]  = *(const bf16x8*)(Abuf + (m * 8 + j) * 8);
                int n  = wn * 64 + t * 16 + lr;
                bfg[t] = *(const bf16x8*)(Bbuf + (n * 8 + j) * 8);
            }
#pragma unroll
            for (int mt = 0; mt < 4; mt++)
#pragma unroll
                for (int nt = 0; nt < 4; nt++)
                    acc[mt][nt] = __builtin_amdgcn_mfma_f32_16x16x32_bf16(
                        af[mt], bfg[nt], acc[mt][nt], 0, 0, 0);
        }
    }

    // ---- epilogue: register exp/pack/rowsum -> u16 LDS repack -> store ----
    // acc frag layout (16x16): col = lr (wave col nt*16+lr), row = quad*4+r.
    const int rowBase = blockIdx.x * 128 + wm * 64;
    const int colBase = blockIdx.y * 128 + wn * 64;
    const float scale = 0.0625f;                 // 1/sqrt(256)
    u16* scw = smem + (size_t)wid * (16 * 72);   // wave-private 16x72 u16
    const int row_l = lane >> 2, cq = lane & 3;

    __syncthreads();   // all waves done reading Abuf/Bbuf; scw aliases them
#pragma unroll
    for (int mt = 0; mt < 4; ++mt){
        float ev[4][4];                          // [nt][r]
#pragma unroll
        for (int nt = 0; nt < 4; nt++)
#pragma unroll
            for (int r = 0; r < 4; r++)
                ev[nt][r] = __expf(acc[mt][nt][r] * scale);  // |arg|<~2: max-free safe
        // row sums: per r, sum 4 nt then reduce across 16 lanes of the quad
#pragma unroll
        for (int r = 0; r < 4; r++){
            float rs = ev[0][r] + ev[1][r] + ev[2][r] + ev[3][r];
            rs += __shfl_xor(rs, 1, 64);
            rs += __shfl_xor(rs, 2, 64);
            rs += __shfl_xor(rs, 4, 64);
            rs += __shfl_xor(rs, 8, 64);
            if (lr == 0)
                atomicAdd(&rowSums[(long)bat * S_LEN + rowBase + mt * 16 + quad * 4 + r], rs);
        }
        // pack to bf16 and repack via wave-private u16 LDS (row-major [16][72])
#pragma unroll
        for (int nt = 0; nt < 4; nt++)
#pragma unroll
            for (int r = 0; r < 4; r++)
                scw[(quad * 4 + r) * 72 + nt * 16 + lr] = f2bf(ev[nt][r]);
        u16x8 pk0 = *(const u16x8*)(scw + row_l * 72 + cq * 16);
        u16x8 pk1 = *(const u16x8*)(scw + row_l * 72 + cq * 16 + 8);
        int row_g = rowBase + mt * 16 + row_l;
        u16* cp = C + (long)bat * cBS + (long)row_g * ldc + colBase + cq * 16;
        *(u16x8*)cp       = pk0;
        *(u16x8*)(cp + 8) = pk1;
    }
}

// ---------------------------------------------------------------------------
// NT GEMM 128x128 tile, DOUBLE-BUFFERED 2-phase prefetch + swizzled LDS.
// (dbuf is right HERE: these grids give only 0.75-2.25 blocks/CU, so TLP
// alone cannot hide latency — R4 A/B: 67.5 -> <49 us.)
// SPLIT>1: bf16 partials at sp*pStride + bat*cBS (pStride in elements).
// SPLIT==1 modes: 0 bf16(+bias), 1 QKV scatter (Q,K natural; V transposed),
//                 2 bias+ReLU, 3 bf16 scaled by 1/rs[row] (ctx).
// Wave layout: 2x2 waves, each owns a 64x64 quadrant (acc[4][4]).
// ---------------------------------------------------------------------------
template<int SPLIT, int MODE>
__global__ __launch_bounds__(256)
void gemm128(const u16* __restrict__ A, int lda,
             const u16* __restrict__ B, int ldb,
             void* __restrict__ Cv, int ldc,
             const u16* __restrict__ bias,
             int K, long aBS, long bBS, long cBS, long pStride,
             const float* __restrict__ rs)
{
    __shared__ __align__(16) u16 smem[4 * 128 * 64];     // 64 KB: 2x(A+B)
    u16* As0 = smem;                      // A buffers: [0], [128*64]
    u16* Bs0 = smem + 2 * 128 * 64;       // B buffers: [0], [128*64]
    const int tid  = threadIdx.x;
    const int lane = tid & 63, wid = tid >> 6;
    const int wm = wid >> 1, wn = wid & 1;
    const int quad = lane >> 4, lr = lane & 15;
    const int jx = lr & 7;

    const int z   = blockIdx.z;
    const int bat = z / SPLIT;
    const int sp  = z % SPLIT;
    const int kLen = K / SPLIT;

    A += (long)bat * aBS + (long)blockIdx.x * 128 * lda + (long)sp * kLen;
    B += (long)bat * bBS + (long)blockIdx.y * 128 * ldb + (long)sp * kLen;

    f32x4 zero = {0.f, 0.f, 0.f, 0.f};
    f32x4 acc[4][4];
#pragma unroll
    for (int i = 0; i < 4; i++)
#pragma unroll
        for (int j = 0; j < 4; j++) acc[i][j] = zero;

    const u16* aP[4]; const u16* bP[4]; int ldst[4];
#pragma unroll
    for (int i = 0; i < 4; i++){
        int u = i * 256 + tid;
        int m = u >> 3, c = u & 7;
        int cs = c ^ (m & 7);                 // pre-swizzled global chunk
        aP[i] = A + (long)m * lda + cs * 8;
        bP[i] = B + (long)m * ldb + cs * 8;
        ldst[i] = u * 8;
    }

    auto stage = [&](int kt, int b){
        const int k0 = kt << 6;
        u16* Ad = As0 + b * (128 * 64);
        u16* Bd = Bs0 + b * (128 * 64);
#pragma unroll
        for (int i = 0; i < 4; i++) async16(aP[i] + k0, Ad + ldst[i]);
#pragma unroll
        for (int i = 0; i < 4; i++) async16(bP[i] + k0, Bd + ldst[i]);
    };

    const int kTiles = kLen >> 6;
    stage(0, 0);
    __syncthreads();                       // drains prologue loads (vmcnt 0)
    for (int kt = 0; kt < kTiles; ++kt){
        const int cur = kt & 1;
        if (kt + 1 < kTiles) stage(kt + 1, cur ^ 1);   // prefetch next tile
        const u16* Ac = As0 + cur * (128 * 64);
        const u16* Bc = Bs0 + cur * (128 * 64);
#pragma unroll
        for (int ks = 0; ks < 2; ++ks){
            const int j = (ks * 4 + quad) ^ jx;
            bf16x8 af[4], bfg[4];
#pragma unroll
            for (int t = 0; t < 4; t++){
                int m  = wm * 64 + t * 16 + lr;
                af[t]  = *(const bf16x8*)(Ac + (m * 8 + j) * 8);
                int n  = wn * 64 + t * 16 + lr;
                bfg[t] = *(const bf16x8*)(Bc + (n * 8 + j) * 8);
            }
#pragma unroll
            for (int mt = 0; mt < 4; mt++)
#pragma unroll
                for (int nt = 0; nt < 4; nt++)
                    acc[mt][nt] = __builtin_amdgcn_mfma_f32_16x16x32_bf16(
                        af[mt], bfg[nt], acc[mt][nt], 0, 0, 0);
        }
        __syncthreads();   // all waves done with buf[cur]; prefetch drained
    }

    const int rowBase = blockIdx.x * 128 + wm * 64;
    const int colBase = blockIdx.y * 128 + wn * 64;
    const int slabw = colBase >> 10;             // wave-uniform (128 | 1024)

    if (MODE == 1 && slabw == 2){
        // ---- V^T path: bias, per-16-col transpose in LDS (u16, stride 72),
        //      store along s.  Wave-private scratch: 16x72 u16 = 2304 B. ----
        u16* scw = smem + (size_t)wid * (16 * 72);
        const int e_l = lane >> 2, sh = lane & 3;
#pragma unroll
        for (int nt = 0; nt < 4; nt++){
            float bv2 = bf2f(bias[colBase + nt * 16 + lr]);
#pragma unroll
            for (int mt = 0; mt < 4; mt++){
                u16x4 pk;
#pragma unroll
                for (int r = 0; r < 4; r++) pk[r] = f2bf(acc[mt][nt][r] + bv2);
                *(u16x4*)(scw + lr * 72 + mt * 16 + quad * 4) = pk;
            }
            const int e_g = (colBase & 1023) + nt * 16 + e_l;
            u16* dst = (u16*)Cv + (long)2 * S_LEN * DMODEL + (long)e_g * S_LEN
                     + rowBase + sh * 16;
            *(u16x8*)(dst)     = *(const u16x8*)(scw + e_l * 72 + sh * 16);
            *(u16x8*)(dst + 8) = *(const u16x8*)(scw + e_l * 72 + sh * 16 + 8);
        }
        return;
    }

    // ---- generic path: per-mt wave-private fp32 repack, coalesced stores ----
    float* scw = (float*)smem + (size_t)wid * (16 * 68);   // 4352 B / wave
    const int row_l = lane >> 2, cq = lane & 3;
#pragma unroll
    for (int mt = 0; mt < 4; ++mt){
#pragma unroll
        for (int nt = 0; nt < 4; nt++)
#pragma unroll
            for (int r = 0; r < 4; r++)
                scw[(quad * 4 + r) * 68 + nt * 16 + lr] = acc[mt][nt][r];
        float vals[16];
#pragma unroll
        for (int j = 0; j < 4; j++)
            *(f32x4*)(vals + j * 4) = *(const f32x4*)(scw + row_l * 68 + cq * 16 + j * 4);
        const int row_g = rowBase + mt * 16 + row_l;
        const int colg  = colBase + cq * 16;
        float inv = 1.f;
        if (MODE == 3) inv = 1.f / rs[(long)bat * S_LEN + row_g];
        float bv[16];
        if (SPLIT == 1 && MODE != 3 && bias){
            u16x8 b0 = *(const u16x8*)(bias + colg);
            u16x8 b1 = *(const u16x8*)(bias + colg + 8);
#pragma unroll
            for (int i = 0; i < 8; i++){ bv[i] = bf2f(b0[i]); bv[8 + i] = bf2f(b1[i]); }
        } else {
#pragma unroll
            for (int i = 0; i < 16; i++) bv[i] = 0.f;
        }
        u16x8 pk0, pk1;
#pragma unroll
        for (int i = 0; i < 16; i++){
            float v = vals[i] + bv[i];
            if (MODE == 2) v = fmaxf(v, 0.f);
            if (MODE == 3) v *= inv;
            if (i < 8) pk0[i] = f2bf(v); else pk1[i - 8] = f2bf(v);
        }
        long idx;
        if (SPLIT > 1)      idx = (long)sp * pStride + (long)bat * cBS + (long)row_g * ldc + colg;
        else if (MODE == 1) idx = ((long)slabw * S_LEN + row_g) * DMODEL + (colg & 1023);
        else                idx = (long)bat * cBS + (long)row_g * ldc + colg;
        u16* cp = (u16*)Cv + idx;
        *(u16x8*)cp       = pk0;
        *(u16x8*)(cp + 8) = pk1;
    }
}

// ---------------------------------------------------------------------------
// merged per-layer prep: weight transposes + Wq|Wk|Wv copy + rowSums zero.
// grid.x = 7728, block (32,8).
// ---------------------------------------------------------------------------
__global__ __launch_bounds__(256)
void wprep(const int* __restrict__ flag, int l,
           const void* Wo, const void* Wf1, const void* Wf2, const void* Wh,
           const void* Wq, const void* Wk, const void* Wv,
           u16* __restrict__ WoT, u16* __restrict__ Wf1T,
           u16* __restrict__ Wf2T, u16* __restrict__ WhT,
           u16* __restrict__ Wcat, float* __restrict__ rowSums)
{
    const int mode = *flag;
    const int z = blockIdx.x;
    const int tx = threadIdx.x, ty = threadIdx.y;

    if (z >= 7680){
        int idx = (z - 7680) * 256 + ty * 32 + tx;   // < 12288
        rowSums[idx] = 0.f;
        return;
    }
    if (z >= 6144){
        int t = ty * 32 + tx;
        long base = (long)(z - 6144) * 2048;
#pragma unroll
        for (int j = 0; j < 8; j++){
            long g = base + j * 256 + t;
            int slab = (int)(g >> 20);
            long r = g & 1048575;
            const void* src = (slab == 0) ? Wq : (slab == 1) ? Wk : Wv;
            Wcat[g] = cvld(src, (long)l * 1048576 + r, mode);
        }
        return;
    }

    const void* in; u16* out; long ib; int R, C, rb, cb;
    if (z < 1024){
        in = Wo; out = WoT; ib = (long)l * 1048576; R = 1024; C = 1024;
        cb = z & 31; rb = z >> 5;
    } else if (z < 3072){
        int t = z - 1024;
        in = Wf1; out = Wf1T; ib = (long)l * 2097152; R = 1024; C = 2048;
        cb = t & 63; rb = t >> 6;
    } else if (z < 5120){
        int t = z - 3072;
        in = Wf2; out = Wf2T; ib = (long)l * 2097152; R = 2048; C = 1024;
        cb = t & 31; rb = t >> 5;
    } else {
        int t = z - 5120;
        int a = t >> 8, u = t & 255;
        in = Wh; out = WhT + (long)a * 262144;
        ib = (long)l * 1048576 + (long)a * 262144; R = 1024; C = 256;
        cb = u & 7; rb = u >> 3;
    }

    __shared__ u16 tbuf[32][34];
    int r0 = rb * 32, c0 = cb * 32;
#pragma unroll
    for (int j = 0; j < 4; j++){
        int r = r0 + ty + j * 8;
        tbuf[ty + j * 8][tx] = cvld(in, ib + (long)r * C + c0 + tx, mode);
    }
    __syncthreads();
#pragma unroll
    for (int j = 0; j < 4; j++){
        int c = c0 + ty + j * 8;
        out[(long)c * R + r0 + tx] = tbuf[tx][ty + j * 8];
    }
}

__global__ __launch_bounds__(256)
void init_h(const int* __restrict__ flag, const void* __restrict__ hin,
            float* __restrict__ h, u16* __restrict__ hbf)
{
    const int mode = *flag;
    long i = (long)blockIdx.x * 256 + threadIdx.x;
    u16 u = cvld(hin, i, mode);
    h[i]   = bf2f(u);
    hbf[i] = u;
}

// bias arena layout (elements)
#define OFF_BQKV 0
#define OFF_BH   12288
#define OFF_BO   16384
#define OFF_BF1  20480
#define OFF_BF2  28672
#define OFF_G1   32768
#define OFF_B1N  36864
#define OFF_G2   40960
#define OFF_B2N  45056
#define OFF_WHD  49152
#define OFF_BHD  53248
#define BIAS_TOT 53252

__global__ __launch_bounds__(256)
void cvt_biases(const int* __restrict__ flag,
                const void* bq, const void* bk, const void* bv, const void* bh,
                const void* bo, const void* bf1, const void* bf2,
                const void* g1, const void* b1n, const void* g2, const void* b2n,
                const void* whd, const void* bhd, u16* __restrict__ A)
{
    int i = blockIdx.x * 256 + threadIdx.x;
    if (i >= BIAS_TOT) return;
    const int mode = *flag;
    u16 v;
    if (i < OFF_BH){
        int l = i / 3072, r = i % 3072;
        const void* p = (r < 1024) ? bq : (r < 2048) ? bk : bv;
        v = cvld(p, (long)l * 1024 + (r & 1023), mode);
    }
    else if (i < OFF_BO)  v = cvld(bh,  i - OFF_BH, mode);
    else if (i < OFF_BF1) v = cvld(bo,  i - OFF_BO, mode);
    else if (i < OFF_BF2) v = cvld(bf1, i - OFF_BF1, mode);
    else if (i < OFF_G1)  v = cvld(bf2, i - OFF_BF2, mode);
    else if (i < OFF_B1N) v = cvld(g1,  i - OFF_G1, mode);
    else if (i < OFF_G2)  v = cvld(b1n, i - OFF_B1N, mode);
    else if (i < OFF_B2N) v = cvld(g2,  i - OFF_G2, mode);
    else if (i < OFF_WHD) v = cvld(b2n, i - OFF_B2N, mode);
    else if (i < OFF_BHD) v = cvld(whd, i - OFF_WHD, mode);
    else                  v = cvld(bhd, i - OFF_BHD, mode);
    A[i] = v;
}

// combined QKV+head bias: bqkvh[z*1024+n] = sum_d b_z[d]*WhT[n,d] + bh[l,n]
__global__ __launch_bounds__(256)
void bias_combine(const u16* __restrict__ arena, const u16* __restrict__ WhT,
                  int l, u16* __restrict__ bqkvh)
{
    int i = blockIdx.x * 256 + threadIdx.x;   // < 3072
    int z = i >> 10, n = i & 1023;
    const u16* bz = arena + OFF_BQKV + l * 3072 + z * 1024;
    const u16* wr = WhT + (long)n * 1024;
    float s = bf2f(arena[OFF_BH + l * 1024 + n]);
    for (int d = 0; d < 1024; d += 8){
        bf16x8 w = *(const bf16x8*)(wr + d);
        bf16x8 b = *(const bf16x8*)(bz + d);
#pragma unroll
        for (int j = 0; j < 8; j++) s += (float)w[j] * (float)b[j];
    }
    bqkvh[i] = f2bf(s);
}

__device__ __forceinline__ float blockSum(float v, float* red){
    int lane = threadIdx.x & 63, wid = threadIdx.x >> 6;
#pragma unroll
    for (int o = 32; o > 0; o >>= 1) v += __shfl_down(v, o, 64);
    __syncthreads();
    if (lane == 0) red[wid] = v;
    __syncthreads();
    return red[0] + red[1] + red[2] + red[3];
}

// h = LN(h + bias + sum_{sp<nparts} bf16 parts[sp]) * g + b
__global__ __launch_bounds__(256)
void ln_fused(float* __restrict__ h, const u16* __restrict__ parts, long pStride,
              int nparts, const u16* __restrict__ bias, u16* __restrict__ hbf,
              const u16* __restrict__ g, const u16* __restrict__ b)
{
    __shared__ float red[4];
    long base = (long)blockIdx.x * DMODEL;
    int tid = threadIdx.x;
    float v[4];
    float s = 0.f;
#pragma unroll
    for (int j = 0; j < 4; j++){
        int c = tid + j * 256;
        float x = bf2f(bias[c]);
        for (int sp = 0; sp < nparts; sp++) x += bf2f(parts[(long)sp * pStride + base + c]);
        float r = h[base + c] + x;
        v[j] = r; s += r;
    }
    float mu = blockSum(s, red) * (1.f / DMODEL);
    float s2 = 0.f;
#pragma unroll
    for (int j = 0; j < 4; j++){ float d = v[j] - mu; s2 += d * d; }
    float var = blockSum(s2, red) * (1.f / DMODEL);
    float inv = rsqrtf(var + 1e-5f);
#pragma unroll
    for (int j = 0; j < 4; j++){
        int c = tid + j * 256;
        float y = (v[j] - mu) * inv * bf2f(g[c]) + bf2f(b[c]);
        h[base + c]   = y;
        hbf[base + c] = f2bf(y);
    }
}

__global__ __launch_bounds__(256)
void head_kernel(const int* __restrict__ flag, const float* __restrict__ h,
                 const u16* __restrict__ arena, const int* __restrict__ nePtr,
                 const int* __restrict__ naPtr, void* __restrict__ outp)
{
    __shared__ float red[4];
    int o = blockIdx.x;
    int ne = *nePtr, na = *naPtr;
    int widx, row;
    if (o < 3 * na){ widx = o / na; row = ne + o % na; }
    else           { widx = 3;      row = o - 3 * na; }
    int tid = threadIdx.x;
    const float* hr = h + (long)row * DMODEL;
    const u16*   w  = arena + OFF_WHD + widx * DMODEL;
    float s = 0.f;
#pragma unroll
    for (int j = 0; j < 4; j++){ int c = tid + j * 256; s += hr[c] * bf2f(w[c]); }
    s = blockSum(s, red);
    if (tid == 0){
        float r = s + bf2f(arena[OFF_BHD + widx]);
        if (*flag) ((float*)outp)[o] = r;
        else       ((u16*)outp)[o]   = f2bf(r);
    }
}

// ---------------------------------------------------------------------------
extern "C" void kernel_launch(void* const* d_in, const int* in_sizes, int n_in,
                              void* d_out, int out_size, void* d_ws, size_t ws_size,
                              hipStream_t stream)
{
    const void* hidden = d_in[0];
    const void* Wq  = d_in[1];  const void* bq  = d_in[2];
    const void* Wk  = d_in[3];  const void* bk  = d_in[4];
    const void* Wv  = d_in[5];  const void* bv  = d_in[6];
    const void* Wh  = d_in[7];  const void* bh  = d_in[8];
    const void* Wo  = d_in[9];  const void* bo  = d_in[10];
    const void* g1  = d_in[11]; const void* b1n = d_in[12];
    const void* g2  = d_in[13]; const void* b2n = d_in[14];
    const void* Wf1 = d_in[15]; const void* bf1 = d_in[16];
    const void* Wf2 = d_in[17]; const void* bf2 = d_in[18];
    const void* Whd = d_in[19]; const void* bhd = d_in[20];
    const int* nePtr = (const int*)d_in[21];
    const int* naPtr = (const int*)d_in[22];

    const long D = 1024, S = 3072, L = 4, DK = 256;

    char* ws = (char*)d_ws;
    size_t off = 0;
    auto alloc = [&](size_t bytes)->char*{
        char* p = ws + off;
        off = (off + bytes + 255) & ~(size_t)255;
        return p;
    };
    int*  flag   = (int*)alloc(256);
    u16*  barena = (u16*)alloc(BIAS_TOT * 2);
    u16*  bqkvh  = (u16*)alloc(3 * D * 2);
    float* rowSums = (float*)alloc(4 * S * 4);
    u16*  WhT    = (u16*)alloc(D * D * 2);
    u16*  WqkvhT = (u16*)alloc(3 * D * D * 2);     // combined (Wz@Wh)^T (3072x1024)
    u16*  WoT    = (u16*)alloc(D * D * 2);
    u16*  Wf1T   = (u16*)alloc(2 * D * D * 2);
    u16*  Wf2T   = (u16*)alloc(2 * D * D * 2);
    float* h     = (float*)alloc(S * D * 4);
    u16*  hbf    = (u16*)alloc(S * D * 2);
    u16*  qkvh   = (u16*)alloc(3 * S * D * 2);     // [Qh;Kh;V^T] (slab 2 = V^T e x s)
    u16*  ctx    = (u16*)alloc(S * D * 2);
    size_t baseEnd = off;

    size_t reg4 = (size_t)4 * S * S * 2;                       // 75.5 MB
    size_t reg1 = (size_t)S * S * 2 + (size_t)S * 2 * D * 2;   // 1-head scores + ffn1
    int HBv = (ws_size >= baseEnd + reg4 + 4096) ? 4 : 1;
    char* regionB = alloc(HBv == 4 ? reg4 : reg1);

    u16* scoresP = (u16*)regionB;
    u16* Wcat    = (u16*)regionB;                  // prep phase (scores dead)
    u16* woParts = (u16*)regionB;                  // 2 x (S*D) bf16 (scores dead)
    u16* ffn1;                                     // (S x 2048) bf16
    u16* f2Parts;                                  // 2 x (S*D) bf16
    if (HBv == 4){
        ffn1    = (u16*)regionB;
        f2Parts = (u16*)(regionB + (size_t)S * 2 * D * 2);
    } else {
        ffn1    = (u16*)(regionB + (size_t)S * S * 2);
        f2Parts = (u16*)regionB;                   // scores dead by FFN2
    }

    const long pSD = S * D;                        // elements per bf16 partial slab

    dim3 tb(32, 8);
    sniff_kernel<<<1, 256, 0, stream>>>((const u16*)hidden, flag);
    cvt_biases<<<(BIAS_TOT + 255) / 256, 256, 0, stream>>>(
        flag, bq, bk, bv, bh, bo, bf1, bf2, g1, b1n, g2, b2n, Whd, bhd, barena);
    init_h<<<(int)(S * D / 256), 256, 0, stream>>>(flag, hidden, h, hbf);

    for (int l = 0; l < L; ++l){
        // ---- prep: transposes + Wcat copy + rowSums zero (1 launch) ----
        wprep<<<7728, tb, 0, stream>>>(flag, l, Wo, Wf1, Wf2, Wh, Wq, Wk, Wv,
                                       WoT, Wf1T, Wf2T, WhT, Wcat, rowSums);
        gemm128<1, 0><<<dim3(8, 8, 3), 256, 0, stream>>>(
            WhT, 1024, Wcat, 1024, WqkvhT, 1024, nullptr,
            1024, 0, (long)D * D, (long)D * D, 0, nullptr);
        bias_combine<<<12, 256, 0, stream>>>(barena, WhT, l, bqkvh);

        // ---- fused QKV+head projection; V written transposed into slab 2 ----
        gemm128<1, 1><<<dim3(24, 24, 1), 256, 0, stream>>>(
            hbf, 1024, WqkvhT, 1024, qkvh, 0, bqkvh,
            1024, 0, 0, 0, 0, nullptr);

        // ---- attention: scores(+exp+rowsums), then ctx with fused /l ----
        if (HBv == 4){
            gemm_scores<<<dim3(24, 24, 4), 256, 0, stream>>>(
                qkvh, 1024, qkvh + S * D, 1024, scoresP, (int)S,
                rowSums, (int)DK, DK, DK, (long)S * S);
            gemm128<1, 3><<<dim3(24, 2, 4), 256, 0, stream>>>(
                scoresP, (int)S, qkvh + 2 * S * D, (int)S,
                ctx, 1024, nullptr, (int)S,
                (long)S * S, (long)DK * S, DK, 0, rowSums);
        } else {
            for (int h0 = 0; h0 < 4; ++h0){
                gemm_scores<<<dim3(24, 24, 1), 256, 0, stream>>>(
                    qkvh + h0 * DK, 1024, qkvh + S * D + h0 * DK, 1024,
                    scoresP, (int)S, rowSums + h0 * S, (int)DK, 0, 0, 0);
                gemm128<1, 3><<<dim3(24, 2, 1), 256, 0, stream>>>(
                    scoresP, (int)S, qkvh + 2 * S * D + (long)h0 * DK * S, (int)S,
                    ctx + h0 * DK, 1024, nullptr, (int)S,
                    0, 0, 0, 0, rowSums + h0 * S);
            }
        }

        // ---- attn_out: split-2 bf16 partials; reduce fused into LN ----
        gemm128<2, 0><<<dim3(24, 8, 2), 256, 0, stream>>>(
            ctx, 1024, WoT, 1024, woParts, 1024, nullptr,
            1024, 0, 0, 0, pSD, nullptr);
        ln_fused<<<3072, 256, 0, stream>>>(h, woParts, pSD, 2, barena + OFF_BO + l * D,
                                           hbf, barena + OFF_G1 + l * D, barena + OFF_B1N + l * D);
        // ---- FFN1: single gemm128, bias+ReLU fused ----
        gemm128<1, 2><<<dim3(24, 16, 1), 256, 0, stream>>>(
            hbf, 1024, Wf1T, 1024, ffn1, 2048, barena + OFF_BF1 + l * 2 * D,
            1024, 0, 0, 0, 0, nullptr);
        // ---- FFN2: split-2 bf16 partials; reduce fused into LN ----
        gemm128<2, 0><<<dim3(24, 8, 2), 256, 0, stream>>>(
            ffn1, 2048, Wf2T, 2048, f2Parts, 1024, nullptr,
            2048, 0, 0, 0, pSD, nullptr);
        ln_fused<<<3072, 256, 0, stream>>>(h, f2Parts, pSD, 2, barena + OFF_BF2 + l * D,
                                           hbf, barena + OFF_G2 + l * D, barena + OFF_B2N + l * D);
    }
    head_kernel<<<out_size, 256, 0, stream>>>(flag, h, barena, nePtr, naPtr, d_out);
}